// Round 7
// baseline (423.390 us; speedup 1.0000x reference)
//
#include <hip/hip_runtime.h>

typedef unsigned short u16;
typedef unsigned int   u32;
typedef unsigned long long u64;

#define HID 128
#define KPB 256      // keys per coarse bucket (shift 8)
#define NBMAX 512    // max coarse buckets (actual: 391)
#define IPB 2048     // incidences per partition workgroup
#define CAP 6144     // LDS val-staging capacity per bucket (mean ~3070)

typedef __bf16 bf16x8 __attribute__((ext_vector_type(8)));
typedef float  f32x4  __attribute__((ext_vector_type(4)));
typedef u32    u32x4  __attribute__((ext_vector_type(4)));

__device__ inline float u2f(u32 u){ union{u32 u;float f;} v; v.u=u; return v.f; }
__device__ inline u32   f2u(float f){ union{float f;u32 u;} v; v.f=f; return v.u; }
__device__ inline u32  f2bfu(float f){ u32 b=f2u(f); return ((b + 0x7FFFu + ((b>>16)&1u))>>16)&0xFFFFu; }
__device__ inline float blo(u32 u){ return u2f(u<<16); }
__device__ inline float bhi(u32 u){ return u2f(u & 0xFFFF0000u); }
__device__ inline u32  pk(float lo, float hi){ return (f2bfu(hi)<<16) | f2bfu(lo); }

// 4-slice table layout: tab[4][M][32] u16 — slice s is a contiguous 3.2 MB block
// (fits the 4 MB per-XCD L2; XCD k = blockIdx%8 touches only slice k&3 -> FETCH
// stays compulsory, r4-verified ~20 MB/pass). k_aggs is ROW-PER-WAVE (r6-verified:
// 71% occupancy, VGPR ~20, zero divergence): 16 4-lane groups each consume one
// incidence's 64 B slice-row per iteration (16 incidences/wave-iter), with a
// 1-deep prefetch so 2 gathers stay in flight per wave. Outputs NT.

// ---------- K1: coarse histogram (blocks [0,nhb)) ∪ W-fragment conversion (rest) ----------
__global__ __launch_bounds__(256) void k_hist_wfrag(const int* __restrict__ nidx, const int* __restrict__ eidx,
                                                    int* __restrict__ hist, int nE, int nN, int nb, int nhb,
                                                    const float* __restrict__ W1, const float* __restrict__ W2,
                                                    u16* __restrict__ W1f, u16* __restrict__ W2f){
    __shared__ int h[NBMAX];
    if ((int)blockIdx.x < nhb){
        for (int t=threadIdx.x; t<nb; t+=256) h[t]=0;
        __syncthreads();
        int base = blockIdx.x*IPB;
        for (int k=threadIdx.x; k<IPB; k+=256){
            int j = base+k;
            if (j < nE){
                atomicAdd(&h[nidx[j]>>8], 1);
                atomicAdd(&h[(nN+eidx[j])>>8], 1);
            }
        }
        __syncthreads();
        for (int t=threadIdx.x; t<nb; t+=256) if (h[t]) atomicAdd(&hist[t], h[t]);
    } else {
        int gid = ((int)blockIdx.x - nhb)*256 + threadIdx.x;   // 32768 total
        const float* W = (gid < 16384) ? W1 : W2;
        u16* Wf = (gid < 16384) ? W1f : W2f;
        int id = gid & 16383;
        int i = id & 7, l = (id>>3)&63, j = (id>>9)&7, s = id>>12;
        Wf[id] = (u16)f2bfu(W[(s*32 + ((l>>4)<<3) + i)*HID + (j<<4) + (l&15)]);
    }
}

// ---------- K2: partition into buckets (blocks [0,npb)) ∪ layer-1 GEMM fp32-A (rest) ----------
// GEMM epilogue writes 4-SLICE-MAJOR: C[((j>>1)*M + row)*32 + (j&1)*16 + c0]
__global__ __launch_bounds__(256) void k_part_gemm(const int* __restrict__ nidx, const int* __restrict__ eidx,
                                                   const int* __restrict__ hist, int* __restrict__ bfill,
                                                   u64* __restrict__ pairs, int nE, int nN, int nb, int npb,
                                                   const float* __restrict__ A, const u16* __restrict__ Wf,
                                                   u16* __restrict__ C, int M){
    __shared__ int h[NBMAX], rsv[NBMAX], fl[NBMAX], bb[NBMAX], sd[256];
    int t = threadIdx.x;
    if ((int)blockIdx.x < npb){
        for (int i=t; i<nb; i+=256){ h[i]=0; fl[i]=0; }
        __syncthreads();
        int base = blockIdx.x*IPB;
        for (int k=t; k<IPB; k+=256){
            int j = base+k;
            if (j < nE){
                atomicAdd(&h[nidx[j]>>8], 1);
                atomicAdd(&h[(nN+eidx[j])>>8], 1);
            }
        }
        int c0 = (2*t   < nb) ? hist[2*t]   : 0;
        int c1 = (2*t+1 < nb) ? hist[2*t+1] : 0;
        int s = c0 + c1;
        sd[t] = s; __syncthreads();
        for (int o=1;o<256;o<<=1){ int u = (t>=o)? sd[t-o] : 0; __syncthreads(); sd[t]+=u; __syncthreads(); }
        int ex = sd[t] - s;
        if (2*t   < nb) bb[2*t]   = ex;
        if (2*t+1 < nb) bb[2*t+1] = ex + c0;
        __syncthreads();
        for (int i=t; i<nb; i+=256){ if (h[i]) rsv[i] = bb[i] + atomicAdd(&bfill[i], h[i]); }
        __syncthreads();
        for (int k=t; k<IPB; k+=256){
            int j = base+k;
            if (j < nE){
                int n = nidx[j], e = eidx[j];
                int b1 = n>>8;
                int p1 = rsv[b1] + atomicAdd(&fl[b1], 1);
                pairs[p1] = ((u64)(u32)n << 32) | (u32)e;
                int k2 = nN + e;
                int b2 = k2>>8;
                int p2 = rsv[b2] + atomicAdd(&fl[b2], 1);
                pairs[p2] = ((u64)(u32)k2 << 32) | (u32)n;
            }
        }
    } else {
        int wave = ((int)blockIdx.x - npb)*4 + (t>>6);
        int lane = t & 63;
        int rtiles = M >> 4;
        if (wave >= rtiles) return;
        int row0 = wave << 4;
        const float* Arow = A + (size_t)(row0 + (lane&15))*HID + ((lane>>4)<<3);
        const bf16x8* Wp = reinterpret_cast<const bf16x8*>(Wf) + lane;
        f32x4 acc[8];
        #pragma unroll
        for (int j=0;j<8;++j) acc[j] = (f32x4){0.f,0.f,0.f,0.f};
        #pragma unroll
        for (int s=0;s<4;++s){
            float4 f0 = *reinterpret_cast<const float4*>(Arow + s*32);
            float4 f1 = *reinterpret_cast<const float4*>(Arow + s*32 + 4);
            union { u16 h[8]; bf16x8 v; } au;
            au.h[0]=(u16)f2bfu(f0.x); au.h[1]=(u16)f2bfu(f0.y); au.h[2]=(u16)f2bfu(f0.z); au.h[3]=(u16)f2bfu(f0.w);
            au.h[4]=(u16)f2bfu(f1.x); au.h[5]=(u16)f2bfu(f1.y); au.h[6]=(u16)f2bfu(f1.z); au.h[7]=(u16)f2bfu(f1.w);
            #pragma unroll
            for (int j=0;j<8;++j){
                bf16x8 b = Wp[(s*8 + j)*64];
                acc[j] = __builtin_amdgcn_mfma_f32_16x16x32_bf16(au.v, b, acc[j], 0, 0, 0);
            }
        }
        int r0 = row0 + ((lane>>4)<<2);
        int c0 = lane & 15;
        #pragma unroll
        for (int j=0;j<8;++j){
            size_t sb = ((size_t)(j>>1)*M)*32 + ((j&1)<<4) + c0;
            #pragma unroll
            for (int r=0;r<4;++r){
                __builtin_nontemporal_store((u16)f2bfu(acc[j][r]), &C[sb + (size_t)(r0+r)*32]);
            }
        }
    }
}

// ---------- per-bucket fine counting sort in LDS (computes own base locally) ----------
__global__ __launch_bounds__(256) void k_bucket(const u64* __restrict__ pairs, const int* __restrict__ hist,
                                                int* __restrict__ csr, int* __restrict__ off,
                                                int nkeys, int nb, int total){
    __shared__ int cntS[KPB];
    __shared__ int fillS[KPB];
    __shared__ int bbS[NBMAX+1];
    __shared__ int sd[256];
    __shared__ int vals[CAP];
    int b = blockIdx.x;
    int t = threadIdx.x;
    if (b == 0 && t == 0) off[nkeys] = total;
    int c0 = (2*t   < nb) ? hist[2*t]   : 0;
    int c1 = (2*t+1 < nb) ? hist[2*t+1] : 0;
    int s = c0 + c1;
    sd[t] = s; __syncthreads();
    for (int o=1;o<256;o<<=1){ int u = (t>=o)? sd[t-o] : 0; __syncthreads(); sd[t]+=u; __syncthreads(); }
    int ex = sd[t] - s;
    if (2*t   <= nb) bbS[2*t]   = ex;
    if (2*t+1 <= nb) bbS[2*t+1] = ex + c0;
    __syncthreads();
    int base = bbS[b];
    int n = bbS[b+1] - base;
    int k0 = b * KPB;

    cntS[t] = 0;
    __syncthreads();
    for (int i=t; i<n; i+=256){
        u64 p = pairs[base+i];
        atomicAdd(&cntS[(int)(p>>32) - k0], 1);
    }
    __syncthreads();
    int c = cntS[t];
    __syncthreads();
    fillS[t] = c; __syncthreads();
    for (int o=1;o<256;o<<=1){ int u = (t>=o)? fillS[t-o] : 0; __syncthreads(); fillS[t]+=u; __syncthreads(); }
    int ex2 = fillS[t] - c;
    __syncthreads();
    fillS[t] = ex2;
    __syncthreads();
    int k = k0 + t;
    if (k < nkeys) off[k] = base + ex2;
    bool fits = (n <= CAP);
    for (int i=t; i<n; i+=256){
        u64 p = pairs[base+i];
        int kl = (int)(p>>32) - k0;
        int pos = atomicAdd(&fillS[kl], 1);
        if (fits) vals[pos] = (int)(u32)p;
        else      csr[base+pos] = (int)(u32)p;
    }
    __syncthreads();
    if (fits){
        for (int i=t; i<n; i+=256) csr[base+i] = vals[i];
    }
}

// ---------- ROW-PER-WAVE 4-slice CSR-gather segment mean ----------
// slice = blockIdx&3 (3.2 MB, L2-resident). One dest row per wave; 16 4-lane
// groups each consume one incidence's 64 B slice-row per iteration (16/iter,
// wave-uniform trip count => zero divergence). Indices prefetched 64-wide
// (one coalesced csr load per window) and delivered by shfl. 1-deep software
// pipeline: next slot's gather is issued before accumulating the current one
// (2 loads in flight/wave). Epilogue: 4-round stride-4 shfl_xor tree; lanes
// 0-3 write the 64 B slice-row (NT).
// MODE 0: out bf16 slice-major | MODE 1: out bf16 row-major, + bias + prelu
// MODE 2: out fp32 row-major, + bias + resid + prelu
template<int MODE>
__global__ __launch_bounds__(256) void k_aggs(const u32* __restrict__ tab, const int* __restrict__ csr,
                                              const int* __restrict__ off, void* __restrict__ outp,
                                              const float* __restrict__ bias, const float* __restrict__ resid,
                                              const float* __restrict__ aptr, int nrows){
    int slice = blockIdx.x & 3;
    int dt    = blockIdx.x >> 2;
    int t = threadIdx.x;
    int lane = t & 63;
    int d = dt*4 + (t>>6);                    // one row per wave
    if (d >= nrows) return;
    int start = off[d], end = off[d+1];
    int deg = end - start;
    int g  = lane >> 2, c4 = lane & 3;        // 16 groups x 4 lanes
    const u32* tslice = tab + (size_t)slice*nrows*16 + (c4<<2);   // slice-row: 16 u32 (64 B)

    float a0=0.f,a1=0.f,a2=0.f,a3=0.f,a4=0.f,a5=0.f,a6=0.f,a7=0.f;
    for (int w = start; w < end; w += 64){
        int widx = csr[w + lane];             // window prefetch (over-read lands in csr/pairs ws)
        int nit = end - w; if (nit > 64) nit = 64;
        int iters = (nit + 15) >> 4;
        // pipeline prologue: issue slot g's gather
        int sl  = g;
        int slc = (sl < nit) ? sl : (nit-1);
        int idx = __shfl(widx, slc, 64);
        u32x4 v = *reinterpret_cast<const u32x4*>(tslice + (size_t)idx*16);
        bool valid = (sl < nit);
        for (int it = 0; it < iters-1; ++it){
            int sl2  = sl + 16;
            int slc2 = (sl2 < nit) ? sl2 : (nit-1);
            int idx2 = __shfl(widx, slc2, 64);
            u32x4 v2 = *reinterpret_cast<const u32x4*>(tslice + (size_t)idx2*16);
            if (!valid) v = (u32x4){0u,0u,0u,0u};
            a0 += blo(v.x); a1 += bhi(v.x);
            a2 += blo(v.y); a3 += bhi(v.y);
            a4 += blo(v.z); a5 += bhi(v.z);
            a6 += blo(v.w); a7 += bhi(v.w);
            v = v2; valid = (sl2 < nit); sl = sl2;
        }
        if (!valid) v = (u32x4){0u,0u,0u,0u};
        a0 += blo(v.x); a1 += bhi(v.x);
        a2 += blo(v.y); a3 += bhi(v.y);
        a4 += blo(v.z); a5 += bhi(v.z);
        a6 += blo(v.w); a7 += bhi(v.w);
    }
    // reduce across the 16 incidence-slot groups (stride-4 lanes share chunk c4)
    #pragma unroll
    for (int m = 4; m < 64; m <<= 1){
        a0 += __shfl_xor(a0, m, 64); a1 += __shfl_xor(a1, m, 64);
        a2 += __shfl_xor(a2, m, 64); a3 += __shfl_xor(a3, m, 64);
        a4 += __shfl_xor(a4, m, 64); a5 += __shfl_xor(a5, m, 64);
        a6 += __shfl_xor(a6, m, 64); a7 += __shfl_xor(a7, m, 64);
    }
    if (g != 0) return;                        // lanes 0-3 hold the 64 B slice-row
    float s = (deg > 0) ? 1.0f/(float)deg : 0.f;
    a0*=s; a1*=s; a2*=s; a3*=s; a4*=s; a5*=s; a6*=s; a7*=s;
    if constexpr (MODE >= 1){
        const f32x4* bp = reinterpret_cast<const f32x4*>(bias + slice*32 + (c4<<3));
        f32x4 b0 = bp[0], b1v = bp[1];
        a0+=b0.x; a1+=b0.y; a2+=b0.z; a3+=b0.w;
        a4+=b1v.x; a5+=b1v.y; a6+=b1v.z; a7+=b1v.w;
        if constexpr (MODE == 2){
            const f32x4* rp = reinterpret_cast<const f32x4*>(resid + (size_t)d*HID + slice*32 + (c4<<3));
            f32x4 r0 = rp[0], r1 = rp[1];
            a0+=r0.x; a1+=r0.y; a2+=r0.z; a3+=r0.w;
            a4+=r1.x; a5+=r1.y; a6+=r1.z; a7+=r1.w;
        }
        float al = aptr[0];
        a0 = (a0>=0.f)? a0 : al*a0;  a1 = (a1>=0.f)? a1 : al*a1;
        a2 = (a2>=0.f)? a2 : al*a2;  a3 = (a3>=0.f)? a3 : al*a3;
        a4 = (a4>=0.f)? a4 : al*a4;  a5 = (a5>=0.f)? a5 : al*a5;
        a6 = (a6>=0.f)? a6 : al*a6;  a7 = (a7>=0.f)? a7 : al*a7;
    }
    if constexpr (MODE == 2){
        f32x4* op = reinterpret_cast<f32x4*>((float*)outp + (size_t)d*HID + slice*32 + (c4<<3));
        __builtin_nontemporal_store((f32x4){a0,a1,a2,a3}, op);
        __builtin_nontemporal_store((f32x4){a4,a5,a6,a7}, op + 1);
    } else if constexpr (MODE == 1){
        // row-major bf16 (feeds the dense GEMM)
        u32x4 wv4 = (u32x4){ pk(a0,a1), pk(a2,a3), pk(a4,a5), pk(a6,a7) };
        __builtin_nontemporal_store(wv4,
            reinterpret_cast<u32x4*>((u32*)outp + (size_t)d*64 + slice*16 + (c4<<2)));
    } else {
        // slice-major bf16 (feeds the next sliced gather)
        u32x4 wv4 = (u32x4){ pk(a0,a1), pk(a2,a3), pk(a4,a5), pk(a6,a7) };
        __builtin_nontemporal_store(wv4,
            reinterpret_cast<u32x4*>((u32*)outp + ((size_t)slice*nrows + d)*16 + (c4<<2)));
    }
}

// ---------- standalone bf16 GEMM: C = A(bf16 row-major) @ Wf, 4-slice-major output ----------
__global__ __launch_bounds__(256) void k_gemm_bf(const u16* __restrict__ A, const u16* __restrict__ Wf,
                                                 u16* __restrict__ C, int M){
    int wave = blockIdx.x*4 + ((int)threadIdx.x>>6);
    int lane = threadIdx.x & 63;
    int rtiles = M >> 4;
    if (wave >= rtiles) return;
    int row0 = wave << 4;
    const u16* Arow = A + (size_t)(row0 + (lane&15))*HID + ((lane>>4)<<3);
    const bf16x8* Wp = reinterpret_cast<const bf16x8*>(Wf) + lane;
    f32x4 acc[8];
    #pragma unroll
    for (int j=0;j<8;++j) acc[j] = (f32x4){0.f,0.f,0.f,0.f};
    #pragma unroll
    for (int s=0;s<4;++s){
        bf16x8 a = *reinterpret_cast<const bf16x8*>(Arow + s*32);
        #pragma unroll
        for (int j=0;j<8;++j){
            bf16x8 b = Wp[(s*8 + j)*64];
            acc[j] = __builtin_amdgcn_mfma_f32_16x16x32_bf16(a, b, acc[j], 0, 0, 0);
        }
    }
    int r0 = row0 + ((lane>>4)<<2);
    int c0 = lane & 15;
    #pragma unroll
    for (int j=0;j<8;++j){
        size_t sb = ((size_t)(j>>1)*M)*32 + ((j&1)<<4) + c0;
        #pragma unroll
        for (int r=0;r<4;++r){
            __builtin_nontemporal_store((u16)f2bfu(acc[j][r]), &C[sb + (size_t)(r0+r)*32]);
        }
    }
}

extern "C" void kernel_launch(void* const* d_in, const int* in_sizes, int n_in,
                              void* d_out, int out_size, void* d_ws, size_t ws_size,
                              hipStream_t stream){
    (void)n_in; (void)out_size; (void)ws_size;
    const float* x  = (const float*)d_in[0];
    const int*  hei = (const int*)  d_in[1];
    const float* W1 = (const float*)d_in[2];
    const float* b1 = (const float*)d_in[3];
    const float* W2 = (const float*)d_in[4];
    const float* b2 = (const float*)d_in[5];
    const float* ap = (const float*)d_in[6];

    const int nN = in_sizes[0] / HID;   // 50000
    const int nE = in_sizes[1] / 2;     // 600000
    const int* nidx = hei;
    const int* eidx = hei + nE;
    const int nkeys = 2*nN;
    const int nb    = (nkeys + KPB - 1) / KPB;   // 391

    char* w = (char*)d_ws;
    size_t o = 0;
    auto alloc = [&](size_t bytes)->void*{
        void* p = (void*)(w + o);
        o += (bytes + 255) & ~(size_t)255;
        return p;
    };
    int* hist  = (int*)alloc((size_t)NBMAX*sizeof(int));
    int* bfill = (int*)alloc((size_t)NBMAX*sizeof(int));
    int* off   = (int*)alloc(((size_t)nkeys+1)*sizeof(int));
    int* csr   = (int*)alloc((size_t)2*nE*sizeof(int));
    u64* pairs = (u64*)alloc((size_t)2*nE*sizeof(u64));
    u16* bufB  = (u16*)alloc((size_t)nN*HID*sizeof(u16));   // xw / hw (4-slice-major)
    u16* bufC  = (u16*)alloc((size_t)nN*HID*sizeof(u16));   // m / m2  (4-slice-major)
    u16* bufH  = (u16*)alloc((size_t)nN*HID*sizeof(u16));   // h (row-major, GEMM input)
    u16* w1f   = (u16*)alloc((size_t)HID*HID*sizeof(u16));
    u16* w2f   = (u16*)alloc((size_t)HID*HID*sizeof(u16));

    hipMemsetAsync(hist, 0, (size_t)2*NBMAX*sizeof(int), stream);   // hist + bfill (contiguous)

    const int pgrid  = (nE + IPB - 1)/IPB;       // 293
    const int rtiles = nN/16;                    // 3125
    const int ggrid  = (rtiles + 3)/4;           // 782
    const int dblk   = (nN + 3)/4;               // 12500 row-tiles (4 rows = 4 waves/block)
    const int agrid  = 4*dblk;                   // × 4 column slices

    // K1: hist ∪ wfrag
    k_hist_wfrag<<<pgrid + 128, 256, 0, stream>>>(nidx, eidx, hist, nE, nN, nb, pgrid, W1, W2, w1f, w2f);
    // K2: part ∪ layer-1 gemm (fp32 A): xw = x @ W1 -> bufB (4-slice-major)
    k_part_gemm<<<pgrid + ggrid, 256, 0, stream>>>(nidx, eidx, hist, bfill, pairs, nE, nN, nb, pgrid,
                                                   x, w1f, bufB, nN);
    // K3: bucket (also writes off sentinel)
    k_bucket<<<nb, 256, 0, stream>>>(pairs, hist, csr, off, nkeys, nb, 2*nE);

    // layer 1: m = B^-1 H^T xw    (hyperedge side) -> bufC (4-slice-major)
    k_aggs<0><<<agrid, 256, 0, stream>>>((const u32*)bufB, csr, off + nN, bufC, nullptr, nullptr, nullptr, nN);
    // h = prelu(D^-1 H m + b1)    (node side) -> bufH (row-major)
    k_aggs<1><<<agrid, 256, 0, stream>>>((const u32*)bufC, csr, off, bufH, b1, nullptr, ap, nN);
    // hw = h @ W2 -> bufB (4-slice-major)
    k_gemm_bf<<<ggrid, 256, 0, stream>>>(bufH, w2f, bufB, nN);
    // layer 2: m2 = B^-1 H^T hw -> bufC (4-slice-major)
    k_aggs<0><<<agrid, 256, 0, stream>>>((const u32*)bufB, csr, off + nN, bufC, nullptr, nullptr, nullptr, nN);
    // out = prelu(D^-1 H m2 + b2 + x)
    k_aggs<2><<<agrid, 256, 0, stream>>>((const u32*)bufC, csr, off, d_out, b2, x, ap, nN);
}

// Round 8
// 240.660 us; speedup vs baseline: 1.7593x; 1.7593x over previous
//
#include <hip/hip_runtime.h>

typedef unsigned short u16;
typedef unsigned int   u32;
typedef unsigned long long u64;

#define HID 128
#define KPB 256      // keys per coarse bucket (shift 8)
#define NBMAX 512    // max coarse buckets (actual: 391)
#define IPB 2048     // incidences per partition workgroup
#define CAP 6144     // LDS val-staging capacity per bucket (mean ~3070)

typedef __bf16 bf16x8 __attribute__((ext_vector_type(8)));
typedef float  f32x4  __attribute__((ext_vector_type(4)));
typedef u32    u32x4  __attribute__((ext_vector_type(4)));

__device__ inline float u2f(u32 u){ union{u32 u;float f;} v; v.u=u; return v.f; }
__device__ inline u32   f2u(float f){ union{float f;u32 u;} v; v.f=f; return v.u; }
__device__ inline u32  f2bfu(float f){ u32 b=f2u(f); return ((b + 0x7FFFu + ((b>>16)&1u))>>16)&0xFFFFu; }
__device__ inline float blo(u32 u){ return u2f(u<<16); }
__device__ inline float bhi(u32 u){ return u2f(u & 0xFFFF0000u); }
__device__ inline u32  pk(float lo, float hi){ return (f2bfu(hi)<<16) | f2bfu(lo); }

// ROW-MAJOR table [M][128] bf16 (256 B rows). k_aggs is ROW-PER-WAVE over FULL rows:
// 4 groups x 16 lanes; each group consumes one incidence's whole 256 B row per iter
// (4 incidences/wave-iter). No slicing -> per-row fixed cost paid ONCE (50K waves/pass,
// 4x fewer than r7), tree is 2 rounds. Table is L3-resident (12.8 MB); occupancy high
// (VGPR ~40) covers the L3 latency. Outputs NT.

// ---------- K1: coarse histogram (blocks [0,nhb)) ∪ W-fragment conversion (rest) ----------
__global__ __launch_bounds__(256) void k_hist_wfrag(const int* __restrict__ nidx, const int* __restrict__ eidx,
                                                    int* __restrict__ hist, int nE, int nN, int nb, int nhb,
                                                    const float* __restrict__ W1, const float* __restrict__ W2,
                                                    u16* __restrict__ W1f, u16* __restrict__ W2f){
    __shared__ int h[NBMAX];
    if ((int)blockIdx.x < nhb){
        for (int t=threadIdx.x; t<nb; t+=256) h[t]=0;
        __syncthreads();
        int base = blockIdx.x*IPB;
        for (int k=threadIdx.x; k<IPB; k+=256){
            int j = base+k;
            if (j < nE){
                atomicAdd(&h[nidx[j]>>8], 1);
                atomicAdd(&h[(nN+eidx[j])>>8], 1);
            }
        }
        __syncthreads();
        for (int t=threadIdx.x; t<nb; t+=256) if (h[t]) atomicAdd(&hist[t], h[t]);
    } else {
        int gid = ((int)blockIdx.x - nhb)*256 + threadIdx.x;   // 32768 total
        const float* W = (gid < 16384) ? W1 : W2;
        u16* Wf = (gid < 16384) ? W1f : W2f;
        int id = gid & 16383;
        int i = id & 7, l = (id>>3)&63, j = (id>>9)&7, s = id>>12;
        Wf[id] = (u16)f2bfu(W[(s*32 + ((l>>4)<<3) + i)*HID + (j<<4) + (l&15)]);
    }
}

// ---------- K2: partition into buckets (blocks [0,npb)) ∪ layer-1 GEMM fp32-A (rest) ----------
// GEMM epilogue writes ROW-MAJOR: C[row*HID + j*16 + c0]
__global__ __launch_bounds__(256) void k_part_gemm(const int* __restrict__ nidx, const int* __restrict__ eidx,
                                                   const int* __restrict__ hist, int* __restrict__ bfill,
                                                   u64* __restrict__ pairs, int nE, int nN, int nb, int npb,
                                                   const float* __restrict__ A, const u16* __restrict__ Wf,
                                                   u16* __restrict__ C, int M){
    __shared__ int h[NBMAX], rsv[NBMAX], fl[NBMAX], bb[NBMAX], sd[256];
    int t = threadIdx.x;
    if ((int)blockIdx.x < npb){
        for (int i=t; i<nb; i+=256){ h[i]=0; fl[i]=0; }
        __syncthreads();
        int base = blockIdx.x*IPB;
        for (int k=t; k<IPB; k+=256){
            int j = base+k;
            if (j < nE){
                atomicAdd(&h[nidx[j]>>8], 1);
                atomicAdd(&h[(nN+eidx[j])>>8], 1);
            }
        }
        int c0 = (2*t   < nb) ? hist[2*t]   : 0;
        int c1 = (2*t+1 < nb) ? hist[2*t+1] : 0;
        int s = c0 + c1;
        sd[t] = s; __syncthreads();
        for (int o=1;o<256;o<<=1){ int u = (t>=o)? sd[t-o] : 0; __syncthreads(); sd[t]+=u; __syncthreads(); }
        int ex = sd[t] - s;
        if (2*t   < nb) bb[2*t]   = ex;
        if (2*t+1 < nb) bb[2*t+1] = ex + c0;
        __syncthreads();
        for (int i=t; i<nb; i+=256){ if (h[i]) rsv[i] = bb[i] + atomicAdd(&bfill[i], h[i]); }
        __syncthreads();
        for (int k=t; k<IPB; k+=256){
            int j = base+k;
            if (j < nE){
                int n = nidx[j], e = eidx[j];
                int b1 = n>>8;
                int p1 = rsv[b1] + atomicAdd(&fl[b1], 1);
                pairs[p1] = ((u64)(u32)n << 32) | (u32)e;
                int k2 = nN + e;
                int b2 = k2>>8;
                int p2 = rsv[b2] + atomicAdd(&fl[b2], 1);
                pairs[p2] = ((u64)(u32)k2 << 32) | (u32)n;
            }
        }
    } else {
        int wave = ((int)blockIdx.x - npb)*4 + (t>>6);
        int lane = t & 63;
        int rtiles = M >> 4;
        if (wave >= rtiles) return;
        int row0 = wave << 4;
        const float* Arow = A + (size_t)(row0 + (lane&15))*HID + ((lane>>4)<<3);
        const bf16x8* Wp = reinterpret_cast<const bf16x8*>(Wf) + lane;
        f32x4 acc[8];
        #pragma unroll
        for (int j=0;j<8;++j) acc[j] = (f32x4){0.f,0.f,0.f,0.f};
        #pragma unroll
        for (int s=0;s<4;++s){
            float4 f0 = *reinterpret_cast<const float4*>(Arow + s*32);
            float4 f1 = *reinterpret_cast<const float4*>(Arow + s*32 + 4);
            union { u16 h[8]; bf16x8 v; } au;
            au.h[0]=(u16)f2bfu(f0.x); au.h[1]=(u16)f2bfu(f0.y); au.h[2]=(u16)f2bfu(f0.z); au.h[3]=(u16)f2bfu(f0.w);
            au.h[4]=(u16)f2bfu(f1.x); au.h[5]=(u16)f2bfu(f1.y); au.h[6]=(u16)f2bfu(f1.z); au.h[7]=(u16)f2bfu(f1.w);
            #pragma unroll
            for (int j=0;j<8;++j){
                bf16x8 b = Wp[(s*8 + j)*64];
                acc[j] = __builtin_amdgcn_mfma_f32_16x16x32_bf16(au.v, b, acc[j], 0, 0, 0);
            }
        }
        int r0 = row0 + ((lane>>4)<<2);
        int c0 = lane & 15;
        #pragma unroll
        for (int j=0;j<8;++j){
            #pragma unroll
            for (int r=0;r<4;++r){
                __builtin_nontemporal_store((u16)f2bfu(acc[j][r]), &C[(size_t)(r0+r)*HID + j*16 + c0]);
            }
        }
    }
}

// ---------- per-bucket fine counting sort in LDS (computes own base locally) ----------
__global__ __launch_bounds__(256) void k_bucket(const u64* __restrict__ pairs, const int* __restrict__ hist,
                                                int* __restrict__ csr, int* __restrict__ off,
                                                int nkeys, int nb, int total){
    __shared__ int cntS[KPB];
    __shared__ int fillS[KPB];
    __shared__ int bbS[NBMAX+1];
    __shared__ int sd[256];
    __shared__ int vals[CAP];
    int b = blockIdx.x;
    int t = threadIdx.x;
    if (b == 0 && t == 0) off[nkeys] = total;
    int c0 = (2*t   < nb) ? hist[2*t]   : 0;
    int c1 = (2*t+1 < nb) ? hist[2*t+1] : 0;
    int s = c0 + c1;
    sd[t] = s; __syncthreads();
    for (int o=1;o<256;o<<=1){ int u = (t>=o)? sd[t-o] : 0; __syncthreads(); sd[t]+=u; __syncthreads(); }
    int ex = sd[t] - s;
    if (2*t   <= nb) bbS[2*t]   = ex;
    if (2*t+1 <= nb) bbS[2*t+1] = ex + c0;
    __syncthreads();
    int base = bbS[b];
    int n = bbS[b+1] - base;
    int k0 = b * KPB;

    cntS[t] = 0;
    __syncthreads();
    for (int i=t; i<n; i+=256){
        u64 p = pairs[base+i];
        atomicAdd(&cntS[(int)(p>>32) - k0], 1);
    }
    __syncthreads();
    int c = cntS[t];
    __syncthreads();
    fillS[t] = c; __syncthreads();
    for (int o=1;o<256;o<<=1){ int u = (t>=o)? fillS[t-o] : 0; __syncthreads(); fillS[t]+=u; __syncthreads(); }
    int ex2 = fillS[t] - c;
    __syncthreads();
    fillS[t] = ex2;
    __syncthreads();
    int k = k0 + t;
    if (k < nkeys) off[k] = base + ex2;
    bool fits = (n <= CAP);
    for (int i=t; i<n; i+=256){
        u64 p = pairs[base+i];
        int kl = (int)(p>>32) - k0;
        int pos = atomicAdd(&fillS[kl], 1);
        if (fits) vals[pos] = (int)(u32)p;
        else      csr[base+pos] = (int)(u32)p;
    }
    __syncthreads();
    if (fits){
        for (int i=t; i<n; i+=256) csr[base+i] = vals[i];
    }
}

// ---------- ROW-PER-WAVE full-row CSR-gather segment mean ----------
// One dest row per wave. 4 groups (g=lane>>4) x 16 lanes (c16): group g consumes
// incidence it*4+g, lane c16 reads 16 B of the 256 B row -> 4 incidences x 2 full
// lines per wave-iter, wave-uniform trip (zero divergence). Indices prefetched
// 64-wide (one coalesced csr load per window), delivered by shfl; 1-deep pipeline
// keeps 2 gathers in flight. Tree: 2 rounds (m=16,32). Lanes 0-15 write the row (NT).
// MODE 0: out bf16 | MODE 1: out bf16 + bias + prelu | MODE 2: fp32 + bias + resid + prelu
template<int MODE>
__global__ __launch_bounds__(256) void k_aggs(const u32* __restrict__ tab, const int* __restrict__ csr,
                                              const int* __restrict__ off, void* __restrict__ outp,
                                              const float* __restrict__ bias, const float* __restrict__ resid,
                                              const float* __restrict__ aptr, int nrows){
    int t = threadIdx.x;
    int lane = t & 63;
    int d = blockIdx.x*4 + (t>>6);            // one row per wave
    if (d >= nrows) return;
    int start = off[d], end = off[d+1];
    int deg = end - start;
    int g = lane >> 4, c16 = lane & 15;       // 4 groups x 16 lanes
    const u32* trow = tab + (c16<<2);         // row stride: 64 u32 (256 B)

    float a0=0.f,a1=0.f,a2=0.f,a3=0.f,a4=0.f,a5=0.f,a6=0.f,a7=0.f;
    for (int w = start; w < end; w += 64){
        int widx = csr[w + lane];             // window prefetch (over-read lands in csr/pairs ws)
        int nit = end - w; if (nit > 64) nit = 64;
        int iters = (nit + 3) >> 2;
        int sl  = g;
        int slc = (sl < nit) ? sl : (nit-1);
        int idx = __shfl(widx, slc, 64);
        u32x4 v = *reinterpret_cast<const u32x4*>(trow + (size_t)idx*64);
        bool valid = (sl < nit);
        for (int it = 0; it < iters-1; ++it){
            int sl2  = sl + 4;
            int slc2 = (sl2 < nit) ? sl2 : (nit-1);
            int idx2 = __shfl(widx, slc2, 64);
            u32x4 v2 = *reinterpret_cast<const u32x4*>(trow + (size_t)idx2*64);
            if (!valid) v = (u32x4){0u,0u,0u,0u};
            a0 += blo(v.x); a1 += bhi(v.x);
            a2 += blo(v.y); a3 += bhi(v.y);
            a4 += blo(v.z); a5 += bhi(v.z);
            a6 += blo(v.w); a7 += bhi(v.w);
            v = v2; valid = (sl2 < nit); sl = sl2;
        }
        if (!valid) v = (u32x4){0u,0u,0u,0u};
        a0 += blo(v.x); a1 += bhi(v.x);
        a2 += blo(v.y); a3 += bhi(v.y);
        a4 += blo(v.z); a5 += bhi(v.z);
        a6 += blo(v.w); a7 += bhi(v.w);
    }
    // reduce across the 4 incidence-slot groups (stride-16 lanes share chunk c16)
    #pragma unroll
    for (int m = 16; m < 64; m <<= 1){
        a0 += __shfl_xor(a0, m, 64); a1 += __shfl_xor(a1, m, 64);
        a2 += __shfl_xor(a2, m, 64); a3 += __shfl_xor(a3, m, 64);
        a4 += __shfl_xor(a4, m, 64); a5 += __shfl_xor(a5, m, 64);
        a6 += __shfl_xor(a6, m, 64); a7 += __shfl_xor(a7, m, 64);
    }
    if (g != 0) return;                        // lanes 0-15 hold the 256 B row
    float s = (deg > 0) ? 1.0f/(float)deg : 0.f;
    a0*=s; a1*=s; a2*=s; a3*=s; a4*=s; a5*=s; a6*=s; a7*=s;
    if constexpr (MODE >= 1){
        const f32x4* bp = reinterpret_cast<const f32x4*>(bias + (c16<<3));
        f32x4 b0 = bp[0], b1v = bp[1];
        a0+=b0.x; a1+=b0.y; a2+=b0.z; a3+=b0.w;
        a4+=b1v.x; a5+=b1v.y; a6+=b1v.z; a7+=b1v.w;
        if constexpr (MODE == 2){
            const f32x4* rp = reinterpret_cast<const f32x4*>(resid + (size_t)d*HID + (c16<<3));
            f32x4 r0 = rp[0], r1 = rp[1];
            a0+=r0.x; a1+=r0.y; a2+=r0.z; a3+=r0.w;
            a4+=r1.x; a5+=r1.y; a6+=r1.z; a7+=r1.w;
        }
        float al = aptr[0];
        a0 = (a0>=0.f)? a0 : al*a0;  a1 = (a1>=0.f)? a1 : al*a1;
        a2 = (a2>=0.f)? a2 : al*a2;  a3 = (a3>=0.f)? a3 : al*a3;
        a4 = (a4>=0.f)? a4 : al*a4;  a5 = (a5>=0.f)? a5 : al*a5;
        a6 = (a6>=0.f)? a6 : al*a6;  a7 = (a7>=0.f)? a7 : al*a7;
    }
    if constexpr (MODE == 2){
        f32x4* op = reinterpret_cast<f32x4*>((float*)outp + (size_t)d*HID + (c16<<3));
        __builtin_nontemporal_store((f32x4){a0,a1,a2,a3}, op);
        __builtin_nontemporal_store((f32x4){a4,a5,a6,a7}, op + 1);
    } else {
        // row-major bf16 (feeds the next gather or the dense GEMM)
        u32x4 wv4 = (u32x4){ pk(a0,a1), pk(a2,a3), pk(a4,a5), pk(a6,a7) };
        __builtin_nontemporal_store(wv4,
            reinterpret_cast<u32x4*>((u32*)outp + (size_t)d*64 + (c16<<2)));
    }
}

// ---------- standalone bf16 GEMM: C = A(bf16 row-major) @ Wf, row-major output ----------
__global__ __launch_bounds__(256) void k_gemm_bf(const u16* __restrict__ A, const u16* __restrict__ Wf,
                                                 u16* __restrict__ C, int M){
    int wave = blockIdx.x*4 + ((int)threadIdx.x>>6);
    int lane = threadIdx.x & 63;
    int rtiles = M >> 4;
    if (wave >= rtiles) return;
    int row0 = wave << 4;
    const u16* Arow = A + (size_t)(row0 + (lane&15))*HID + ((lane>>4)<<3);
    const bf16x8* Wp = reinterpret_cast<const bf16x8*>(Wf) + lane;
    f32x4 acc[8];
    #pragma unroll
    for (int j=0;j<8;++j) acc[j] = (f32x4){0.f,0.f,0.f,0.f};
    #pragma unroll
    for (int s=0;s<4;++s){
        bf16x8 a = *reinterpret_cast<const bf16x8*>(Arow + s*32);
        #pragma unroll
        for (int j=0;j<8;++j){
            bf16x8 b = Wp[(s*8 + j)*64];
            acc[j] = __builtin_amdgcn_mfma_f32_16x16x32_bf16(a, b, acc[j], 0, 0, 0);
        }
    }
    int r0 = row0 + ((lane>>4)<<2);
    int c0 = lane & 15;
    #pragma unroll
    for (int j=0;j<8;++j){
        #pragma unroll
        for (int r=0;r<4;++r){
            __builtin_nontemporal_store((u16)f2bfu(acc[j][r]), &C[(size_t)(r0+r)*HID + j*16 + c0]);
        }
    }
}

extern "C" void kernel_launch(void* const* d_in, const int* in_sizes, int n_in,
                              void* d_out, int out_size, void* d_ws, size_t ws_size,
                              hipStream_t stream){
    (void)n_in; (void)out_size; (void)ws_size;
    const float* x  = (const float*)d_in[0];
    const int*  hei = (const int*)  d_in[1];
    const float* W1 = (const float*)d_in[2];
    const float* b1 = (const float*)d_in[3];
    const float* W2 = (const float*)d_in[4];
    const float* b2 = (const float*)d_in[5];
    const float* ap = (const float*)d_in[6];

    const int nN = in_sizes[0] / HID;   // 50000
    const int nE = in_sizes[1] / 2;     // 600000
    const int* nidx = hei;
    const int* eidx = hei + nE;
    const int nkeys = 2*nN;
    const int nb    = (nkeys + KPB - 1) / KPB;   // 391

    char* w = (char*)d_ws;
    size_t o = 0;
    auto alloc = [&](size_t bytes)->void*{
        void* p = (void*)(w + o);
        o += (bytes + 255) & ~(size_t)255;
        return p;
    };
    int* hist  = (int*)alloc((size_t)NBMAX*sizeof(int));
    int* bfill = (int*)alloc((size_t)NBMAX*sizeof(int));
    int* off   = (int*)alloc(((size_t)nkeys+1)*sizeof(int));
    int* csr   = (int*)alloc((size_t)2*nE*sizeof(int));
    u64* pairs = (u64*)alloc((size_t)2*nE*sizeof(u64));
    u16* bufB  = (u16*)alloc((size_t)nN*HID*sizeof(u16));   // xw / hw (row-major)
    u16* bufC  = (u16*)alloc((size_t)nN*HID*sizeof(u16));   // m / m2  (row-major)
    u16* bufH  = (u16*)alloc((size_t)nN*HID*sizeof(u16));   // h (row-major)
    u16* w1f   = (u16*)alloc((size_t)HID*HID*sizeof(u16));
    u16* w2f   = (u16*)alloc((size_t)HID*HID*sizeof(u16));

    hipMemsetAsync(hist, 0, (size_t)2*NBMAX*sizeof(int), stream);   // hist + bfill (contiguous)

    const int pgrid  = (nE + IPB - 1)/IPB;       // 293
    const int rtiles = nN/16;                    // 3125
    const int ggrid  = (rtiles + 3)/4;           // 782
    const int agrid  = (nN + 3)/4;               // 12500 (one row per wave, 4 waves/block)

    // K1: hist ∪ wfrag
    k_hist_wfrag<<<pgrid + 128, 256, 0, stream>>>(nidx, eidx, hist, nE, nN, nb, pgrid, W1, W2, w1f, w2f);
    // K2: part ∪ layer-1 gemm (fp32 A): xw = x @ W1 -> bufB (row-major)
    k_part_gemm<<<pgrid + ggrid, 256, 0, stream>>>(nidx, eidx, hist, bfill, pairs, nE, nN, nb, pgrid,
                                                   x, w1f, bufB, nN);
    // K3: bucket (also writes off sentinel)
    k_bucket<<<nb, 256, 0, stream>>>(pairs, hist, csr, off, nkeys, nb, 2*nE);

    // layer 1: m = B^-1 H^T xw    (hyperedge side) -> bufC
    k_aggs<0><<<agrid, 256, 0, stream>>>((const u32*)bufB, csr, off + nN, bufC, nullptr, nullptr, nullptr, nN);
    // h = prelu(D^-1 H m + b1)    (node side) -> bufH
    k_aggs<1><<<agrid, 256, 0, stream>>>((const u32*)bufC, csr, off, bufH, b1, nullptr, ap, nN);
    // hw = h @ W2 -> bufB
    k_gemm_bf<<<ggrid, 256, 0, stream>>>(bufH, w2f, bufB, nN);
    // layer 2: m2 = B^-1 H^T hw -> bufC
    k_aggs<0><<<agrid, 256, 0, stream>>>((const u32*)bufB, csr, off + nN, bufC, nullptr, nullptr, nullptr, nN);
    // out = prelu(D^-1 H m2 + b2 + x)
    k_aggs<2><<<agrid, 256, 0, stream>>>((const u32*)bufC, csr, off, d_out, b2, x, ap, nN);
}